// Round 4
// baseline (403.579 us; speedup 1.0000x reference)
//
#include <hip/hip_runtime.h>
#include <math.h>

// Hierarchy molemap: per-row hierarchical softmax over 65 leaf logits.
// Output 0: leaf_path_probs [N,65]; Output 1: node_probs [N,76], concatenated.
//
// v4: persistent single-wave blocks, double-buffered async DMA with counted
// vmcnt(9) (batch k+1 loads in flight under batch k compute+stores).
// Buffers sized 32x76 words: node staging overlays the consumed input buffer,
// so LDS stays 19456 B/block -> 8 blocks/CU (same occupancy as v2/v3).
// Non-temporal output stores kept (neutral measured, theoretically >=).

#define NLEAF 65
#define NNODE 76
#define ROWS  32          // rows per batch (one batch per buffer)
#define TPB   64
#define GRIDMAX 2048      // 8 blocks/CU * 256 CU

#define IN_F4   ((ROWS * NLEAF) / 4)        // 520 float4 per batch
#define IN_FULL (IN_F4 / TPB)               // 8 full rounds
#define IN_TAIL (IN_F4 - IN_FULL * TPB)     // 8 leftover
#define ND_F4   ((ROWS * NNODE) / 4)        // 608 float4 per batch
#define ND_FULL (ND_F4 / TPB)               // 9 full rounds
#define ND_TAIL (ND_F4 - ND_FULL * TPB)     // 32 leftover
#define BUFW    (ROWS * NNODE)              // 2432 floats per buffer

typedef float f32x4 __attribute__((ext_vector_type(4)));

__device__ __forceinline__ void async_copy16(const float4* g, float4* l) {
    __builtin_amdgcn_global_load_lds(
        (const __attribute__((address_space(1))) void*)g,
        (__attribute__((address_space(3))) void*)l,
        16, 0, 0);
}

__device__ __forceinline__ void dma_batch(const float* __restrict__ x,
                                          size_t r0, float* buf, int tid) {
    const float4* __restrict__ src4 = (const float4*)(x + r0 * NLEAF);
    float4* d4 = (float4*)buf;
#pragma unroll
    for (int i = 0; i < IN_FULL; ++i)
        async_copy16(src4 + tid + i * TPB, d4 + tid + i * TPB);
    if (tid < IN_TAIL)
        async_copy16(src4 + tid + IN_FULL * TPB, d4 + tid + IN_FULL * TPB);
}

// v: leaf logits in, leaf probs out. p2: level-2 probs. pt0/pt1: top probs.
__device__ __forceinline__ void row_softmax(float* __restrict__ v,
                                            float* __restrict__ p2,
                                            float& pt0, float& pt1) {
    constexpr int ga[8] = {0, 7, 30, 48, 53, 58, 59, 62};
    constexpr int gb[8] = {7, 30, 48, 53, 58, 59, 62, 65};

    float gsum[8], means[8];
#pragma unroll
    for (int g = 0; g < 8; ++g) {
        float mx = -INFINITY, sx = 0.0f;
#pragma unroll
        for (int i = ga[g]; i < gb[g]; ++i) { mx = fmaxf(mx, v[i]); sx += v[i]; }
        gsum[g]  = sx;
        means[g] = sx * (1.0f / (float)(gb[g] - ga[g]));
        float denom = 0.0f;
#pragma unroll
        for (int i = ga[g]; i < gb[g]; ++i) {
            float e = __expf(v[i] - mx);
            v[i] = e;
            denom += e;
        }
        float inv = 1.0f / denom;
#pragma unroll
        for (int i = ga[g]; i < gb[g]; ++i) v[i] *= inv;
    }

    float m0 = (gsum[0] + gsum[1] + gsum[2] + gsum[3]) * (1.0f / 53.0f);
    float m1 = (gsum[4] + gsum[5] + gsum[6] + gsum[7]) * (1.0f / 12.0f);
    float mt = fmaxf(m0, m1);
    float e0 = __expf(m0 - mt), e1 = __expf(m1 - mt);
    float invt = 1.0f / (e0 + e1);
    pt0 = e0 * invt; pt1 = e1 * invt;

    float mxa = fmaxf(fmaxf(means[0], means[1]), fmaxf(means[2], means[3]));
    float sa = 0.0f;
#pragma unroll
    for (int g = 0; g < 4; ++g) { p2[g] = __expf(means[g] - mxa); sa += p2[g]; }
    float inva = 1.0f / sa;
#pragma unroll
    for (int g = 0; g < 4; ++g) p2[g] *= inva;

    float mxb = fmaxf(fmaxf(means[4], means[5]), fmaxf(means[6], means[7]));
    float sb = 0.0f;
#pragma unroll
    for (int g = 4; g < 8; ++g) { p2[g] = __expf(means[g] - mxb); sb += p2[g]; }
    float invb = 1.0f / sb;
#pragma unroll
    for (int g = 4; g < 8; ++g) p2[g] *= invb;
}

__global__ __launch_bounds__(TPB, 2) void hier_molemap_kernel(
    const float* __restrict__ x,
    float* __restrict__ out_leaf,   // [N,65]
    float* __restrict__ out_node,   // [N,76]
    int N)
{
    __shared__ float lds[2][BUFW];   // 2*2432*4 = 19456 B -> 8 blocks/CU
    const int tid = threadIdx.x;

    const int nbatch  = (N + ROWS - 1) / ROWS;
    const int nblocks = (int)gridDim.x;
    const int per = (nbatch + nblocks - 1) / nblocks;
    const int b0  = blockIdx.x * per;
    const int b1  = min(nbatch, b0 + per);
    if (b0 >= b1) return;

    float* cur = lds[0];
    float* nxt = lds[1];

    constexpr int ga[8] = {0, 7, 30, 48, 53, 58, 59, 62};
    constexpr int gb[8] = {7, 30, 48, 53, 58, 59, 62, 65};

    // ---- prologue: DMA first batch if full ----
    if (N - b0 * ROWS >= ROWS)
        dma_batch(x, (size_t)b0 * ROWS, cur, tid);

    for (int b = b0; b < b1; ++b) {
        const size_t r0 = (size_t)b * ROWS;
        const bool full      = ((size_t)N - r0 >= ROWS);
        const bool next_full = (b + 1 < b1) && ((size_t)N - (r0 + ROWS) >= ROWS);

        // ---- issue DMA for next batch into nxt (overlaps everything below) ----
        if (next_full) {
            asm volatile("" ::: "memory");
            dma_batch(x, r0 + ROWS, nxt, tid);
        }

        if (full) {
            // wait for current batch's 9 DMA loads; the 9 just-issued next-batch
            // loads may stay in flight (loads complete in order among loads).
            if (next_full) asm volatile("s_waitcnt vmcnt(9)" ::: "memory");
            else           asm volatile("s_waitcnt vmcnt(0)" ::: "memory");

            float v[NLEAF];
            float p2[8];
            float pt0 = 0.0f, pt1 = 0.0f;

            if (tid < ROWS) {
                const float* __restrict__ r = cur + tid * NLEAF;
#pragma unroll
                for (int i = 0; i < NLEAF; ++i) v[i] = r[i];

                row_softmax(v, p2, pt0, pt1);

                // leaf path probs into own LDS row in place (stride 65)
                float* __restrict__ w = cur + tid * NLEAF;
#pragma unroll
                for (int g = 0; g < 8; ++g) {
                    float f = p2[g] * ((g < 4) ? pt0 : pt1);
#pragma unroll
                    for (int i = ga[g]; i < gb[g]; ++i) w[i] = v[i] * f;
                }
            }
            // same-wave cross-lane LDS RAW: in-order DS pipe + insurance wait
            asm volatile("s_waitcnt lgkmcnt(0)" ::: "memory");

            // ---- leaf store: coalesced LDS -> out_leaf (nt) ----
            {
                f32x4* __restrict__ dst4 = (f32x4*)(out_leaf + r0 * NLEAF);
                const f32x4* s4 = (const f32x4*)cur;
#pragma unroll
                for (int i = 0; i < IN_FULL; ++i) {
                    int q = tid + i * TPB;
                    __builtin_nontemporal_store(s4[q], dst4 + q);
                }
                if (tid < IN_TAIL) {
                    int q = tid + IN_FULL * TPB;
                    __builtin_nontemporal_store(s4[q], dst4 + q);
                }
            }
            asm volatile("" ::: "memory");

            // ---- node staging overlays cur (stride 76, rows 16B-aligned) ----
            if (tid < ROWS) {
                float4* __restrict__ nrow4 = (float4*)cur + tid * (NNODE / 4);
#pragma unroll
                for (int c = 0; c < 16; ++c) {
                    float4 t;
                    t.x = v[4 * c + 0];
                    t.y = v[4 * c + 1];
                    t.z = v[4 * c + 2];
                    t.w = v[4 * c + 3];
                    nrow4[c] = t;
                }
                float4 t16; t16.x = v[64];  t16.y = p2[0]; t16.z = p2[1]; t16.w = p2[2];
                nrow4[16] = t16;
                float4 t17; t17.x = p2[3];  t17.y = p2[4]; t17.z = p2[5]; t17.w = p2[6];
                nrow4[17] = t17;
                float4 t18; t18.x = p2[7];  t18.y = pt0;   t18.z = pt1;   t18.w = 1.0f;
                nrow4[18] = t18;
            }
            asm volatile("s_waitcnt lgkmcnt(0)" ::: "memory");

            // ---- node store: flat LDS -> out_node (nt, layouts identical) ----
            {
                f32x4* __restrict__ dst4 = (f32x4*)(out_node + r0 * NNODE);
                const f32x4* s4 = (const f32x4*)cur;
#pragma unroll
                for (int i = 0; i < ND_FULL; ++i) {
                    int q = tid + i * TPB;
                    __builtin_nontemporal_store(s4[q], dst4 + q);
                }
                if (tid < ND_TAIL) {
                    int q = tid + ND_FULL * TPB;
                    __builtin_nontemporal_store(s4[q], dst4 + q);
                }
            }
        } else {
            // ---- scalar fallback: partial batch (globally last one only) ----
            const int R = (int)((size_t)N - r0);
            if (tid < R) {
                float v[NLEAF];
                float p2[8];
                float pt0, pt1;
                const float* __restrict__ src = x + (r0 + tid) * NLEAF;
#pragma unroll
                for (int i = 0; i < NLEAF; ++i) v[i] = src[i];
                row_softmax(v, p2, pt0, pt1);
                float* __restrict__ dl = out_leaf + (r0 + tid) * NLEAF;
                float* __restrict__ dn = out_node + (r0 + tid) * NNODE;
#pragma unroll
                for (int g = 0; g < 8; ++g) {
                    float f = p2[g] * ((g < 4) ? pt0 : pt1);
#pragma unroll
                    for (int i = ga[g]; i < gb[g]; ++i) dl[i] = v[i] * f;
                }
#pragma unroll
                for (int i = 0; i < NLEAF; ++i) dn[i] = v[i];
#pragma unroll
                for (int g = 0; g < 8; ++g) dn[NLEAF + g] = p2[g];
                dn[73] = pt0;
                dn[74] = pt1;
                dn[75] = 1.0f;
            }
        }

        // swap buffers
        float* t = cur; cur = nxt; nxt = t;
    }
}

extern "C" void kernel_launch(void* const* d_in, const int* in_sizes, int n_in,
                              void* d_out, int out_size, void* d_ws, size_t ws_size,
                              hipStream_t stream) {
    const float* x = (const float*)d_in[0];
    int N = in_sizes[0] / NLEAF;

    float* out_leaf = (float*)d_out;                       // [N,65]
    float* out_node = (float*)d_out + (size_t)N * NLEAF;   // [N,76]

    int nbatch = (N + ROWS - 1) / ROWS;
    int grid   = nbatch < GRIDMAX ? nbatch : GRIDMAX;
    hier_molemap_kernel<<<grid, TPB, 0, stream>>>(x, out_leaf, out_node, N);
}

// Round 5
// 385.530 us; speedup vs baseline: 1.0468x; 1.0468x over previous
//
#include <hip/hip_runtime.h>
#include <math.h>

// Hierarchy molemap: per-row hierarchical softmax over 65 leaf logits.
// Output 0: leaf_path_probs [N,65]; Output 1: node_probs [N,76], concatenated.
//
// FINAL (v2, measured best 386.3 us): single-wave blocks (64 rows, 64
// threads), barrier-free except one post-DMA wait. Input staged via
// global_load_lds dwordx4 into a flat stride-65 region; node probs staged at
// stride 76 (16B-aligned rows, LDS layout == global layout, so the node store
// is a flat float4 copy). 19456 B LDS -> 8 blocks/CU; non-persistent grid
// provides DMA/compute overlap across resident blocks (TLP).
//
// Falsified alternatives (kept for the record):
//   v1 128-row 2-wave + 4 barriers: 393.4 (barrier drains not the cost)
//   v3b nt output stores:           388.9 (no store-allocate penalty)
//   v4 persistent + vmcnt(9) dbuf:  403.6 (DMA latency already TLP-hidden)

#define NLEAF 65
#define NNODE 76
#define ROWS  64
#define TPB   64

#define NF4    ((ROWS * NLEAF) / 4)   // 1040 float4 (input/leaf region)
#define NQ4    ((ROWS * NNODE) / 4)   // 1216 float4 (node region)
#define FULL_A (NF4 / TPB)            // 16 full rounds
#define TAIL_A (NF4 - FULL_A * TPB)   // 16 leftover float4
#define FULL_E (NQ4 / TPB)            // 19 exact rounds

__device__ __forceinline__ void async_copy16(const float4* g, float4* l) {
    __builtin_amdgcn_global_load_lds(
        (const __attribute__((address_space(1))) void*)g,
        (__attribute__((address_space(3))) void*)l,
        16, 0, 0);
}

__global__ __launch_bounds__(TPB, 2) void hier_molemap_kernel(
    const float* __restrict__ x,
    float* __restrict__ out_leaf,   // [N,65]
    float* __restrict__ out_node,   // [N,76]
    int N)
{
    // 64*76*4 = 19456 B -> 8 blocks/CU. Region reused: first as packed
    // stride-65 input/leaf rows (4160 words), then as stride-76 node rows.
    __shared__ float lds[ROWS * NNODE];

    const int tid  = threadIdx.x;
    const int row0 = blockIdx.x * ROWS;
    if (row0 >= N) return;
    const int R    = min(ROWS, N - row0);
    const bool full = (R == ROWS);

    // ---------- Phase A: global -> LDS (async DMA, flat) ----------
    if (full) {
        const float4* __restrict__ src4 = (const float4*)(x + (size_t)row0 * NLEAF);
        float4* lds4 = (float4*)lds;
#pragma unroll
        for (int i = 0; i < FULL_A; ++i)
            async_copy16(src4 + tid + i * TPB, lds4 + tid + i * TPB);
        if (tid < TAIL_A)
            async_copy16(src4 + tid + FULL_A * TPB, lds4 + tid + FULL_A * TPB);
    } else {
        const float* __restrict__ src = x + (size_t)row0 * NLEAF;
        for (int i = tid; i < R * NLEAF; i += TPB) lds[i] = src[i];
    }
    // Single wave: only need the DMA drained before reading LDS.
    __syncthreads();

    // ---------- Compute (thread t owns row t) ----------
    float v[NLEAF];
    float p2[8];
    float pt0 = 0.0f, pt1 = 0.0f;

    constexpr int ga[8] = {0, 7, 30, 48, 53, 58, 59, 62};
    constexpr int gb[8] = {7, 30, 48, 53, 58, 59, 62, 65};

    if (tid < R) {
        const float* __restrict__ r = lds + tid * NLEAF;
#pragma unroll
        for (int i = 0; i < NLEAF; ++i) v[i] = r[i];

        float gsum[8], means[8];
#pragma unroll
        for (int g = 0; g < 8; ++g) {
            float mx = -INFINITY, sx = 0.0f;
#pragma unroll
            for (int i = ga[g]; i < gb[g]; ++i) { mx = fmaxf(mx, v[i]); sx += v[i]; }
            gsum[g]  = sx;
            means[g] = sx * (1.0f / (float)(gb[g] - ga[g]));
            float denom = 0.0f;
#pragma unroll
            for (int i = ga[g]; i < gb[g]; ++i) {
                float e = __expf(v[i] - mx);
                v[i] = e;
                denom += e;
            }
            float inv = 1.0f / denom;
#pragma unroll
            for (int i = ga[g]; i < gb[g]; ++i) v[i] *= inv;
        }

        float m0 = (gsum[0] + gsum[1] + gsum[2] + gsum[3]) * (1.0f / 53.0f);
        float m1 = (gsum[4] + gsum[5] + gsum[6] + gsum[7]) * (1.0f / 12.0f);
        float mt = fmaxf(m0, m1);
        float e0 = __expf(m0 - mt), e1 = __expf(m1 - mt);
        float invt = 1.0f / (e0 + e1);
        pt0 = e0 * invt; pt1 = e1 * invt;

        float mxa = fmaxf(fmaxf(means[0], means[1]), fmaxf(means[2], means[3]));
        float sa = 0.0f;
#pragma unroll
        for (int g = 0; g < 4; ++g) { p2[g] = __expf(means[g] - mxa); sa += p2[g]; }
        float inva = 1.0f / sa;
#pragma unroll
        for (int g = 0; g < 4; ++g) p2[g] *= inva;

        float mxb = fmaxf(fmaxf(means[4], means[5]), fmaxf(means[6], means[7]));
        float sb = 0.0f;
#pragma unroll
        for (int g = 4; g < 8; ++g) { p2[g] = __expf(means[g] - mxb); sb += p2[g]; }
        float invb = 1.0f / sb;
#pragma unroll
        for (int g = 4; g < 8; ++g) p2[g] *= invb;

        // write leaf_path_probs into own LDS row in place
        float* __restrict__ w = lds + tid * NLEAF;
#pragma unroll
        for (int g = 0; g < 8; ++g) {
            float f = p2[g] * ((g < 4) ? pt0 : pt1);
#pragma unroll
            for (int i = ga[g]; i < gb[g]; ++i) w[i] = v[i] * f;
        }
    }
    // Same-wave cross-lane LDS RAW: DS pipe is in-order; cheap insurance wait
    // (drains LDS only — NOT global stores).
    asm volatile("s_waitcnt lgkmcnt(0)" ::: "memory");

    // ---------- Phase C: coalesced LDS -> out_leaf ----------
    if (full) {
        float4* __restrict__ dst4 = (float4*)(out_leaf + (size_t)row0 * NLEAF);
        const float4* lds4 = (const float4*)lds;
#pragma unroll
        for (int i = 0; i < FULL_A; ++i) {
            int idx = tid + i * TPB;
            dst4[idx] = lds4[idx];
        }
        if (tid < TAIL_A) {
            int idx = tid + FULL_A * TPB;
            dst4[idx] = lds4[idx];
        }
    } else {
        float* __restrict__ dst = out_leaf + (size_t)row0 * NLEAF;
        for (int i = tid; i < R * NLEAF; i += TPB) dst[i] = lds[i];
    }
    // WAR: Phase D overwrites what C read. Same wave + in-order DS; make sure
    // all C reads have landed before D's writes issue.
    asm volatile("s_waitcnt lgkmcnt(0)" ::: "memory");

    // ---------- Phase D: node rows, stride 76 (rows 16B-aligned), b128 writes ----------
    if (tid < R) {
        float4* __restrict__ nrow4 = (float4*)lds + tid * (NNODE / 4);
#pragma unroll
        for (int c = 0; c < 16; ++c) {
            float4 t;
            t.x = v[4 * c + 0];
            t.y = v[4 * c + 1];
            t.z = v[4 * c + 2];
            t.w = v[4 * c + 3];
            nrow4[c] = t;
        }
        float4 t16; t16.x = v[64];  t16.y = p2[0]; t16.z = p2[1]; t16.w = p2[2];
        nrow4[16] = t16;
        float4 t17; t17.x = p2[3];  t17.y = p2[4]; t17.z = p2[5]; t17.w = p2[6];
        nrow4[17] = t17;
        float4 t18; t18.x = p2[7];  t18.y = pt0;   t18.z = pt1;   t18.w = 1.0f;
        nrow4[18] = t18;
    }
    asm volatile("s_waitcnt lgkmcnt(0)" ::: "memory");

    // ---------- Phase E: flat LDS -> out_node (layouts identical, no div) ----------
    if (full) {
        float4* __restrict__ dst4 = (float4*)(out_node + (size_t)row0 * NNODE);
        const float4* lds4 = (const float4*)lds;
#pragma unroll
        for (int i = 0; i < FULL_E; ++i) {
            int q = tid + i * TPB;   // NQ4 = 1216 = 19*64 exact
            dst4[q] = lds4[q];
        }
    } else {
        float* __restrict__ dst = out_node + (size_t)row0 * NNODE;
        for (int j = tid; j < R * NNODE; j += TPB) {
            dst[j] = lds[j];
        }
    }
}

extern "C" void kernel_launch(void* const* d_in, const int* in_sizes, int n_in,
                              void* d_out, int out_size, void* d_ws, size_t ws_size,
                              hipStream_t stream) {
    const float* x = (const float*)d_in[0];
    int N = in_sizes[0] / NLEAF;

    float* out_leaf = (float*)d_out;                       // [N,65]
    float* out_node = (float*)d_out + (size_t)N * NLEAF;   // [N,76]

    int grid = (N + ROWS - 1) / ROWS;
    hier_molemap_kernel<<<grid, TPB, 0, stream>>>(x, out_leaf, out_node, N);
}